// Round 10
// baseline (149.858 us; speedup 1.0000x reference)
//
#include <hip/hip_runtime.h>
#include <hip/hip_bf16.h>

typedef __attribute__((ext_vector_type(4))) float f32x4;
typedef __attribute__((ext_vector_type(8))) short bf16x8;

#define NN 131072      // minibatch nodes
#define TT 100000      // rows per featured type table
#define DD 512         // raw feature dim
#define EE 256         // embedding size
#define NT_MAX 1026    // worst-case GEMM tiles (128 rows each)

__device__ inline ushort f2bf(float f) {
    union { float f; unsigned u; } x; x.f = f;
    unsigned r = x.u + 0x7fffu + ((x.u >> 16) & 1u);
    return (ushort)(r >> 16);
}

__device__ inline void gload16(const void* g, void* l) {
    __builtin_amdgcn_global_load_lds(
        (const __attribute__((address_space(1))) unsigned int*)g,
        (__attribute__((address_space(3))) unsigned int*)l, 16, 0, 0);
}

// counted-vmcnt barrier: loads stay in flight across the barrier (T4)
#define WAIT_BAR(N) do {                                   \
    asm volatile("s_waitcnt vmcnt(" #N ")" ::: "memory");  \
    __builtin_amdgcn_s_barrier();                          \
    __builtin_amdgcn_sched_barrier(0);                     \
} while (0)

// ---------------- prep: W (D x E, f32) -> Wt (E x D, bf16); also zero cnt ----
__global__ void prep_w_kernel(const float* __restrict__ W0, const float* __restrict__ W1,
                              ushort* __restrict__ Wt0, ushort* __restrict__ Wt1,
                              int* __restrict__ cnt) {
    if (blockIdx.x == 0 && threadIdx.x < 4) cnt[threadIdx.x] = 0;
    int gid = blockIdx.x * 256 + threadIdx.x;   // 65536 total = 2 * 512 * 64
    int t = gid >> 15;
    int rem = gid & 32767;
    int d = rem >> 6, eg = rem & 63;
    const float* W = t ? W1 : W0;
    ushort* Wt = t ? Wt1 : Wt0;
    f32x4 v = *(const f32x4*)(W + d * EE + eg * 4);
#pragma unroll
    for (int j = 0; j < 4; ++j)
        Wt[(size_t)(eg * 4 + j) * DD + d] = f2bf(v[j]);
}

// ---------------- compact: ballot+popc, one atomic per block per type --------
__global__ void compact_kernel(const int* __restrict__ tids, int* __restrict__ cnt,
                               int* __restrict__ l0, int* __restrict__ l1) {
    const int i = blockIdx.x * 256 + threadIdx.x;   // grid exact: 512*256 = NN
    const int t = tids[i];
    const int lane = threadIdx.x & 63, wid = threadIdx.x >> 6;
    unsigned long long b0 = __ballot(t == 0);
    unsigned long long b1 = __ballot(t == 1);
    __shared__ int w0[4], w1[4];
    __shared__ int base0, base1;
    if (lane == 0) { w0[wid] = __popcll(b0); w1[wid] = __popcll(b1); }
    __syncthreads();
    if (threadIdx.x == 0) {
        base0 = atomicAdd(&cnt[0], w0[0] + w0[1] + w0[2] + w0[3]);
        base1 = atomicAdd(&cnt[1], w1[0] + w1[1] + w1[2] + w1[3]);
    }
    __syncthreads();
    int p0 = 0, p1 = 0;
#pragma unroll
    for (int w = 0; w < 4; ++w) if (w < wid) { p0 += w0[w]; p1 += w1[w]; }
    const unsigned long long ltm = (1ull << lane) - 1ull;
    if (t == 0)      l0[base0 + p0 + __popcll(b0 & ltm)] = i;
    else if (t == 1) l1[base1 + p1 + __popcll(b1 & ltm)] = i;
}

// ---------------- embedding gather for tids >= 2 ----------------
__global__ void emb_gather_kernel(const int* __restrict__ ids, const int* __restrict__ tids,
                                  const float* __restrict__ emb, float* __restrict__ out) {
    int gid = blockIdx.x * 256 + threadIdx.x;   // N*64 total, float4 granularity
    int i = gid >> 6, j = gid & 63;
    if (tids[i] >= 2) {
        ((f32x4*)out)[(size_t)i * 64 + j] = ((const f32x4*)emb)[(size_t)ids[i] * 64 + j];
    }
}

// ---------------- fused gathered-A GEMM, 3-deep counted-vmcnt pipeline -------
// out[list[r]] = bf16(feats[type_ids[list[r]]]) @ W. BM=128,BN=256,BK=32.
// 512 thr = 8 waves (4M x 2N). 4 LDS buffers; stage(k+3) each iter; barriers
// use counted vmcnt(8) so 2 stages of loads stay in flight continuously.
// A staged f32 direct-to-LDS (gathered src, inverse-swizzled h^(row&7) on 16B);
// B staged bf16 (inverse-swizzled (col^(col>>2))&3 on 16B).
__global__ __launch_bounds__(512) void gemm_gather_kernel(
    const int* __restrict__ l0, const int* __restrict__ l1,
    const int* __restrict__ cntp, const int* __restrict__ type_ids,
    const float* __restrict__ feats0, const float* __restrict__ feats1,
    const ushort* __restrict__ Wt0, const ushort* __restrict__ Wt1,
    float* __restrict__ out) {
    const int cnt0 = cntp[0], cnt1 = cntp[1];
    const int nt0 = (cnt0 + 127) >> 7;
    const int nt1 = (cnt1 + 127) >> 7;
    const int b = blockIdx.x;
    const int* list; const float* feats; const ushort* Wt; int cnt, tile;
    if (b < nt0)             { tile = b;       list = l0; feats = feats0; Wt = Wt0; cnt = cnt0; }
    else if (b < nt0 + nt1)  { tile = b - nt0; list = l1; feats = feats1; Wt = Wt1; cnt = cnt1; }
    else return;
    const int row0 = tile * 128;

    __shared__ char Alds[4][16384];   // f32: row*128B, 16B units swizzled h^(row&7)
    __shared__ char Blds[4][16384];   // bf16: col*64B, 16B segs swizzled (col^(col>>2))&3

    const int tid = threadIdx.x;
    const int lane = tid & 63, wid = tid >> 6;
    const int wr = wid >> 1, wc = wid & 1;      // wave tile: 32 rows x 128 cols
    const int ln15 = lane & 15, lq = lane >> 4;

    // ---- staging sources (per-lane, inverse-swizzled; +kk*32 walks K) ----
    // A: dest d = p*8192 + tid*16 -> row = p*64 + (tid>>3), hp = tid&7,
    //    logical half hl = hp ^ (row&7); 16B = 4 f32
    const float* asrc[2];
#pragma unroll
    for (int p = 0; p < 2; ++p) {
        int row = p * 64 + (tid >> 3);
        int rg = row0 + row;
        int g = (rg < cnt) ? type_ids[list[rg]] : 0;
        int hl = (tid & 7) ^ (row & 7);
        asrc[p] = feats + (size_t)g * DD + hl * 4;
    }
    // B: dest d = p*8192 + tid*16 -> col = p*128 + (tid>>2), sp = tid&3,
    //    logical seg sl = sp ^ ((col^(col>>2))&3); 16B = 8 bf16
    const ushort* bsrc[2];
#pragma unroll
    for (int p = 0; p < 2; ++p) {
        int col = p * 128 + (tid >> 2);
        int sl = (tid & 3) ^ ((col ^ (col >> 2)) & 3);
        bsrc[p] = Wt + (size_t)col * DD + sl * 8;
    }

    auto stage = [&](int buf, int kk) {   // 4 wave-instrs, 32 KB/block, fire-and-forget
        gload16(asrc[0] + kk * 32, &Alds[buf][tid * 16]);
        gload16(asrc[1] + kk * 32, &Alds[buf][8192 + tid * 16]);
        gload16(bsrc[0] + kk * 32, &Blds[buf][tid * 16]);
        gload16(bsrc[1] + kk * 32, &Blds[buf][8192 + tid * 16]);
    };

    f32x4 acc[2][8] = {};

    auto compute = [&](int buf) {   // 16 MFMA/wave (K=32)
        const char* Ab = Alds[buf];
        const char* Bb = Blds[buf];
        const int ra0 = wr * 32 + ln15, ra1 = ra0 + 16;
        const int h0 = lq * 2, h1 = h0 + 1;
        f32x4 a0lo = *(const f32x4*)(Ab + ra0 * 128 + ((h0 ^ (ra0 & 7)) << 4));
        f32x4 a0hi = *(const f32x4*)(Ab + ra0 * 128 + ((h1 ^ (ra0 & 7)) << 4));
        f32x4 a1lo = *(const f32x4*)(Ab + ra1 * 128 + ((h0 ^ (ra1 & 7)) << 4));
        f32x4 a1hi = *(const f32x4*)(Ab + ra1 * 128 + ((h1 ^ (ra1 & 7)) << 4));
        bf16x8 A0, A1;
#pragma unroll
        for (int j = 0; j < 4; ++j) {
            A0[j]     = (short)f2bf(a0lo[j]);
            A0[j + 4] = (short)f2bf(a0hi[j]);
            A1[j]     = (short)f2bf(a1lo[j]);
            A1[j + 4] = (short)f2bf(a1hi[j]);
        }
#pragma unroll
        for (int ni = 0; ni < 8; ++ni) {
            int col = wc * 128 + ni * 16 + ln15;
            int baddr = col * 64 + ((lq ^ ((col ^ (col >> 2)) & 3)) << 4);
            bf16x8 bfr = *(const bf16x8*)(Bb + baddr);
            acc[0][ni] = __builtin_amdgcn_mfma_f32_16x16x32_bf16(A0, bfr, acc[0][ni], 0, 0, 0);
            acc[1][ni] = __builtin_amdgcn_mfma_f32_16x16x32_bf16(A1, bfr, acc[1][ni], 0, 0, 0);
        }
    };

    // ---- prologue: 3 stages in flight (12 outstanding vmem/wave)
    stage(0, 0); stage(1, 1); stage(2, 2);

    // ---- main loop: wait to 8 (stage kk done, 2 stages still flying),
    //      barrier (cross-wave visibility + buffer-reuse safety), refill.
    for (int kk = 0; kk < 13; ++kk) {
        WAIT_BAR(8);
        stage((kk + 3) & 3, kk + 3);
        compute(kk & 3);
    }
    WAIT_BAR(8);  compute(1);   // kk=13
    WAIT_BAR(4);  compute(2);   // kk=14
    WAIT_BAR(0);  compute(3);   // kk=15

    // ---- epilogue: scatter rows to out[node]
#pragma unroll
    for (int mi = 0; mi < 2; ++mi) {
        int mbase = row0 + wr * 32 + mi * 16 + lq * 4;
#pragma unroll
        for (int rr = 0; rr < 4; ++rr) {
            int r = mbase + rr;
            if (r < cnt) {
                int nd = list[r];
                float* orow = out + (size_t)nd * EE + wc * 128 + ln15;
#pragma unroll
                for (int ni = 0; ni < 8; ++ni) orow[ni * 16] = acc[mi][ni][rr];
            }
        }
    }
}

extern "C" void kernel_launch(void* const* d_in, const int* in_sizes, int n_in,
                              void* d_out, int out_size, void* d_ws, size_t ws_size,
                              hipStream_t stream) {
    const int*   node_ids  = (const int*)d_in[0];
    const int*   node_tids = (const int*)d_in[1];
    const int*   type_ids  = (const int*)d_in[2];
    const float* feats0    = (const float*)d_in[3];
    const float* feats1    = (const float*)d_in[4];
    const float* W0        = (const float*)d_in[5];
    const float* W1        = (const float*)d_in[6];
    const float* node_emb  = (const float*)d_in[7];
    float* out = (float*)d_out;

    char* ws = (char*)d_ws;
    int* cnt = (int*)ws;                              // 16 B
    int* l0  = (int*)(ws + 16);                       // N ints
    int* l1  = (int*)(ws + 16 + 524288);              // N ints
    ushort* Wt0 = (ushort*)(ws + 16 + 2 * 524288);    // 256 KB
    ushort* Wt1 = Wt0 + DD * EE;                      // 256 KB

    prep_w_kernel<<<256, 256, 0, stream>>>(W0, W1, Wt0, Wt1, cnt);
    compact_kernel<<<512, 256, 0, stream>>>(node_tids, cnt, l0, l1);
    emb_gather_kernel<<<32768, 256, 0, stream>>>(node_ids, node_tids, node_emb, out);
    gemm_gather_kernel<<<NT_MAX, 512, 0, stream>>>(l0, l1, cnt, type_ids,
                                                   feats0, feats1, Wt0, Wt1, out);
}